// Round 14
// baseline (88.700 us; speedup 1.0000x reference)
//
#include <hip/hip_runtime.h>

#define G_ 32
#define S_ 512
#define D_ 128
#define H_ 8
#define BM_ (G_*S_)
#define EPSF 1e-6f
#define VP_ 516   // vlT row stride (shorts): 1032B == 2 banks -> 16 rows hit 16 distinct even banks

typedef float f32x4  __attribute__((ext_vector_type(4)));
typedef float f32x16 __attribute__((ext_vector_type(16)));
typedef short s16x8  __attribute__((ext_vector_type(8)));

typedef unsigned int uint32;

#if __has_builtin(__builtin_amdgcn_exp2f)
#define EXP2F(x) __builtin_amdgcn_exp2f(x)
#else
#define EXP2F(x) exp2f(x)
#endif

static __device__ __forceinline__ unsigned short f2bf(float f){
  uint32 u = __float_as_uint(f);
  u = (u + 0x7fffu + ((u >> 16) & 1u)) >> 16;
  return (unsigned short)u;
}
static __device__ __forceinline__ float bf2f(unsigned short h){
  return __uint_as_float(((uint32)h) << 16);
}
static __device__ __forceinline__ float siluf(float x){
  float e = EXP2F(-x * 1.4426950408889634f);
  return x / (1.0f + e);
}
static __device__ __forceinline__ float geluf(float x){
  float y = 0.7978845608028654f * (x + 0.044715f * x * x * x);
  y = fminf(fmaxf(y, -40.0f), 40.0f);
  float e = EXP2F(y * 2.8853900817779268f);   // e^{2y}
  float th = (e - 1.0f) / (e + 1.0f);
  return 0.5f * x * (1.0f + th);
}
static __device__ __forceinline__ uint32 sad3(uint32 a, uint32 b){
#if __has_builtin(__builtin_amdgcn_sad_u8)
  return __builtin_amdgcn_sad_u8(a, b, 0u);
#else
  uint32 d; uint32 z = 0;
  asm("v_sad_u8 %0, %1, %2, %3" : "=v"(d) : "v"(a), "v"(b), "v"(z));
  return d;
#endif
}

// ---------------- all weight transposes, one flat launch --------------------
__global__ __launch_bounds__(256) void k_wprep_all(
    const float* __restrict__ w0, const float* __restrict__ w1,
    const float* __restrict__ w2, const float* __restrict__ w3,
    const float* __restrict__ w4, const float* __restrict__ w5,
    const float* __restrict__ w6, const float* __restrict__ w7,
    unsigned short* __restrict__ o0, unsigned short* __restrict__ o1,
    unsigned short* __restrict__ o2, unsigned short* __restrict__ o3,
    unsigned short* __restrict__ o4, unsigned short* __restrict__ o5,
    unsigned short* __restrict__ o6, unsigned short* __restrict__ o7){
  const int id = blockIdx.x * 256 + threadIdx.x;   // 0..180223
  const float* W; unsigned short* O; int Kd, Nd, lid;
  if (id < 81920){
    const int which = id >> 14;
    W = (which == 0) ? w0 : (which == 1) ? w1 : (which == 2) ? w2 : (which == 3) ? w3 : w4;
    O = (which == 0) ? o0 : (which == 1) ? o1 : (which == 2) ? o2 : (which == 3) ? o3 : o4;
    Kd = 128; Nd = 128; lid = id & 16383;
  } else if (id < 114688){ W = w5; O = o5; Kd = 128; Nd = 256; lid = id - 81920; }
  else if (id < 147456){   W = w6; O = o6; Kd = 128; Nd = 256; lid = id - 114688; }
  else if (id < 180224){   W = w7; O = o7; Kd = 256; Nd = 128; lid = id - 147456; }
  else return;
  const int n = lid / Kd, k = lid - n * Kd;
  O[lid] = f2bf(W[(size_t)k * Nd + n]);
}

// ---------------- QKVG projections, y-split 2 (QK | VG), fused rms1 ---------
// grid (256 rowblocks of 64, 2), 256 thr. x read 2x (was 4x), pe 1x (was 2x).
// Both weight matrices LDS-staged: 2 x 128x132 shorts = 66 KB -> 2 blocks/CU.
__global__ __launch_bounds__(256) void k_qkvg2(
    const float* __restrict__ x, const float* __restrict__ pe,
    const float* __restrict__ ln1,
    const unsigned short* __restrict__ wqt, const unsigned short* __restrict__ wkt,
    const unsigned short* __restrict__ wvt, const unsigned short* __restrict__ wgt,
    unsigned short* __restrict__ qbf, unsigned short* __restrict__ kbf,
    unsigned short* __restrict__ vbf, unsigned short* __restrict__ gbf){
  __shared__ unsigned short w0l[128 * 132];
  __shared__ unsigned short w1l[128 * 132];
  const int y = blockIdx.y;
  const unsigned short* W0 = y ? wvt : wqt;
  const unsigned short* W1 = y ? wgt : wkt;
  unsigned short* out0 = y ? vbf : qbf;
  unsigned short* out1 = y ? gbf : kbf;
  const float scale0 = y ? 1.0f : 0.36067376022224085f;   // HD^-0.5*log2e on q
  const int tid = threadIdx.x;
  #pragma unroll
  for (int c = 0; c < 8; ++c){
    const int id8 = c * 256 + tid;          // 0..2047 -> 128 rows x 16 uint4
    const int n = id8 >> 4, k8 = id8 & 15;
    *(uint4*)&w0l[n * 132 + k8 * 8] = *(const uint4*)&W0[n * 128 + k8 * 8];
    *(uint4*)&w1l[n * 132 + k8 * 8] = *(const uint4*)&W1[n * 128 + k8 * 8];
  }
  const int lane = tid & 63, wave = tid >> 6;
  const int lr = lane & 15, lh = lane >> 4;
  const int rowbase = blockIdx.x * 64 + wave * 16;
  const size_t xb = (size_t)(rowbase + lr) * 128 + lh * 8;
  // fused rms1 in GEMM layout: lane owns 32 elems (cols kc*32+lh*8..+7)
  float xv[32];
  float ss = 0.f;
  #pragma unroll
  for (int kc = 0; kc < 4; ++kc){
    const float4 a = *(const float4*)&x[xb + kc * 32];
    const float4 b = *(const float4*)&x[xb + kc * 32 + 4];
    xv[kc*8+0]=a.x; xv[kc*8+1]=a.y; xv[kc*8+2]=a.z; xv[kc*8+3]=a.w;
    xv[kc*8+4]=b.x; xv[kc*8+5]=b.y; xv[kc*8+6]=b.z; xv[kc*8+7]=b.w;
    ss += a.x*a.x + a.y*a.y + a.z*a.z + a.w*a.w;
    ss += b.x*b.x + b.y*b.y + b.z*b.z + b.w*b.w;
  }
  ss += __shfl_xor(ss, 16, 64);
  ss += __shfl_xor(ss, 32, 64);
  const float rs = rsqrtf(ss * (1.0f / 128.0f) + EPSF);
  s16x8 af[4];
  #pragma unroll
  for (int kc = 0; kc < 4; ++kc){
    const float4 w0 = *(const float4*)&ln1[kc * 32 + lh * 8];
    const float4 w1 = *(const float4*)&ln1[kc * 32 + lh * 8 + 4];
    float n0 = xv[kc*8+0]*rs*w0.x, n1 = xv[kc*8+1]*rs*w0.y;
    float n2 = xv[kc*8+2]*rs*w0.z, n3 = xv[kc*8+3]*rs*w0.w;
    float n4 = xv[kc*8+4]*rs*w1.x, n5 = xv[kc*8+5]*rs*w1.y;
    float n6 = xv[kc*8+6]*rs*w1.z, n7 = xv[kc*8+7]*rs*w1.w;
    if (y == 0){
      const float4 p0 = *(const float4*)&pe[xb + kc * 32];
      const float4 p1 = *(const float4*)&pe[xb + kc * 32 + 4];
      n0 += p0.x; n1 += p0.y; n2 += p0.z; n3 += p0.w;
      n4 += p1.x; n5 += p1.y; n6 += p1.z; n7 += p1.w;
    }
    s16x8 r;
    r[0]=(short)f2bf(n0); r[1]=(short)f2bf(n1); r[2]=(short)f2bf(n2); r[3]=(short)f2bf(n3);
    r[4]=(short)f2bf(n4); r[5]=(short)f2bf(n5); r[6]=(short)f2bf(n6); r[7]=(short)f2bf(n7);
    af[kc] = r;
  }
  __syncthreads();
  #pragma unroll
  for (int m = 0; m < 2; ++m){
    const unsigned short* wl = m ? w1l : w0l;
    unsigned short* out = m ? out1 : out0;
    const float scale = m ? 1.0f : scale0;
    #pragma unroll
    for (int ct = 0; ct < 8; ++ct){
      f32x4 acc = (f32x4)(0.0f);
      #pragma unroll
      for (int kc = 0; kc < 4; ++kc)
        acc = __builtin_amdgcn_mfma_f32_16x16x32_bf16(af[kc],
                *(const s16x8*)&wl[(ct * 16 + lr) * 132 + kc * 32 + lh * 8], acc, 0, 0, 0);
      #pragma unroll
      for (int j = 0; j < 4; ++j){
        const int row = rowbase + lh * 4 + j;
        const int col = ct * 16 + lr;
        out[(size_t)row * 128 + col] = f2bf(acc[j] * scale);
      }
    }
  }
}

// ---------------- retention attention: (g,head,qtile) per block -------------
// R11 best-passing structure: K from global (L2), e2 from LDS table.
__global__ __launch_bounds__(256, 4) void k_attn(const unsigned short* __restrict__ qb,
    const unsigned short* __restrict__ kb, const unsigned short* __restrict__ vb,
    const int* __restrict__ coords, unsigned short* __restrict__ ob){
  __shared__ unsigned short vlT[16 * VP_];     // 16.1 KB
  __shared__ uint32 cl1[S_];                   // 2 KB
  __shared__ float e2tab[384];                 // 1.5 KB
  const int bx = blockIdx.x;
  const int g = bx >> 5, head = (bx >> 2) & 7, qtile = bx & 3;
  const int tid = threadIdx.x;
  const size_t rb = (size_t)g * S_ * 128 + head * 16;
  const int lane = tid & 63, wave = tid >> 6;
  const int lq = lane & 31, half = lane >> 5;
  const int qrow = qtile * 128 + wave * 32 + lq;
  const s16x8 bq = *(const s16x8*)(qb + rb + (size_t)qrow * 128 + half * 8);  // before barrier
  const float decay2 = log2f(1.0f - EXP2F(-(float)(5 + head)));
  #pragma unroll
  for (int r = tid; r < S_; r += 256){
    const int4 cc = ((const int4*)coords)[g * S_ + r];
    cl1[r] = (uint32)(cc.y & 127) | ((uint32)(cc.z & 127) << 8) | ((uint32)(cc.w & 127) << 16);
  }
  for (int d = tid; d < 384; d += 256)
    e2tab[d] = EXP2F((float)d * decay2);       // same expression as inline -> bitwise equal
  {
    const int r0 = tid * 2;
    const unsigned short* v0 = vb + rb + (size_t)r0 * 128;
    const uint4 a0 = ((const uint4*)v0)[0], a1 = ((const uint4*)v0)[1];
    const uint4 b0 = ((const uint4*)(v0 + 128))[0], b1 = ((const uint4*)(v0 + 128))[1];
    const unsigned short* pa0 = (const unsigned short*)&a0;
    const unsigned short* pa1 = (const unsigned short*)&a1;
    const unsigned short* pb0 = (const unsigned short*)&b0;
    const unsigned short* pb1 = (const unsigned short*)&b1;
    #pragma unroll
    for (int hd = 0; hd < 8; ++hd){
      *(uint32*)&vlT[hd * VP_ + r0] = (uint32)pa0[hd] | ((uint32)pb0[hd] << 16);
      *(uint32*)&vlT[(hd + 8) * VP_ + r0] = (uint32)pa1[hd] | ((uint32)pb1[hd] << 16);
    }
  }
  __syncthreads();
  const uint32 cs = cl1[qrow];
  f32x16 accO = (f32x16)(0.0f);
  float2 zm0 = {0.f,0.f}, zm1 = {0.f,0.f}, zm2 = {0.f,0.f}, zm3 = {0.f,0.f};
  const int vrow = (lq & 15) * VP_;
  for (int tc = 0; tc < 16; ++tc){
    // K fragment straight from global (L2-resident)
    const s16x8 ak = *(const s16x8*)(kb + rb + (size_t)(tc * 32 + lq) * 128 + half * 8);
    const uint4 cq0 = *(const uint4*)&cl1[tc * 32 + 4 * half];
    const uint4 cq1 = *(const uint4*)&cl1[tc * 32 + 8 + 4 * half];
    const uint4 cq2 = *(const uint4*)&cl1[tc * 32 + 16 + 4 * half];
    const uint4 cq3 = *(const uint4*)&cl1[tc * 32 + 24 + 4 * half];
    // e2 lookups are independent of the MFMA result -> issue early
    float e2v[16];
    #pragma unroll
    for (int i = 0; i < 16; ++i){
      const uint4& cq = (i < 4) ? cq0 : (i < 8) ? cq1 : (i < 12) ? cq2 : cq3;
      e2v[i] = e2tab[sad3(cs, (&cq.x)[i & 3])];
    }
    const f32x16 c = __builtin_amdgcn_mfma_f32_32x32x16_bf16(ak, bq, (f32x16)(0.0f), 0, 0, 0);
    float wv[16];
    #pragma unroll
    for (int i = 0; i < 16; ++i){
      const float e1 = EXP2F(c[i]);        // exp(qk) (log2e folded into q)
      const float e2 = e2v[i];
      wv[i] = e1 * e2;
      float2& zm = (i & 2) ? ((i & 1) ? zm3 : zm2) : ((i & 1) ? zm1 : zm0);
      zm.x += e1; zm.y += e2;
    }
    union { uint32 u[4]; s16x8 v; } f0, f1;
    #pragma unroll
    for (int j = 0; j < 4; ++j){
      asm("v_cvt_pk_bf16_f32 %0, %1, %2" : "=v"(f0.u[j]) : "v"(wv[2 * j]), "v"(wv[2 * j + 1]));
      asm("v_cvt_pk_bf16_f32 %0, %1, %2" : "=v"(f1.u[j]) : "v"(wv[8 + 2 * j]), "v"(wv[9 + 2 * j]));
    }
    const int vcol = tc * 32 + 4 * half;
    union { uint32 u[4]; s16x8 v; } bv0, bv1;
    *(uint2*)&bv0.u[0] = *(const uint2*)&vlT[vrow + vcol];
    *(uint2*)&bv0.u[2] = *(const uint2*)&vlT[vrow + vcol + 8];
    *(uint2*)&bv1.u[0] = *(const uint2*)&vlT[vrow + vcol + 16];
    *(uint2*)&bv1.u[2] = *(const uint2*)&vlT[vrow + vcol + 24];
    accO = __builtin_amdgcn_mfma_f32_32x32x16_bf16(f0.v, bv0.v, accO, 0, 0, 0);
    accO = __builtin_amdgcn_mfma_f32_32x32x16_bf16(f1.v, bv1.v, accO, 0, 0, 0);
  }
  float Z = (zm0.x + zm1.x) + (zm2.x + zm3.x);
  float M = (zm0.y + zm1.y) + (zm2.y + zm3.y);
  Z += __shfl_xor(Z, 32, 64);
  M += __shfl_xor(M, 32, 64);
  const float sc = Z * sqrtf(M);          // denom==1 always (mask rowsum<=1)
  const float epsp = EPSF * sc * sc;
  const size_t qbase = (size_t)(g * S_ + qtile * 128 + wave * 32);
  const int sub = (lq >> 4);
  #pragma unroll
  for (int ii = 0; ii < 8; ++ii){
    const int i = sub * 8 + ii;
    const int r = (i & 3) + 8 * (i >> 2) + 4 * half;
    const float v = accO[i];
    float ss = v * v;
    ss += __shfl_xor(ss, 1, 64); ss += __shfl_xor(ss, 2, 64);
    ss += __shfl_xor(ss, 4, 64); ss += __shfl_xor(ss, 8, 64);
    const float ei = __shfl(epsp, r, 64);
    const float on = v * rsqrtf(ss * 0.0625f + ei);
    ob[(qbase + r) * 128 + head * 16 + (lq & 15)] = f2bf(on);
  }
}

// ---------------- Wo GEMM, LDS-staged weights, col-split --------------------
__global__ __launch_bounds__(256) void k_wo(const unsigned short* __restrict__ g,
    const unsigned short* __restrict__ o, const unsigned short* __restrict__ WT,
    const float* __restrict__ resid, float* __restrict__ outp){
  __shared__ unsigned short wt[64 * 136];
  const int y = blockIdx.y;
  const int tid = threadIdx.x;
  #pragma unroll
  for (int c = 0; c < 4; ++c){
    const int id8 = c * 256 + tid;
    const int n = id8 >> 4, k8 = id8 & 15;
    *(uint4*)&wt[n * 136 + k8 * 8] = *(const uint4*)&WT[(size_t)(y * 64 + n) * 128 + k8 * 8];
  }
  const int lane = tid & 63, wave = tid >> 6;
  const int lr = lane & 15, lh = lane >> 4;
  const int rowbase = blockIdx.x * 64 + wave * 16;
  s16x8 af[4];
  const size_t abase = (size_t)(rowbase + lr) * 128 + lh * 8;
  #pragma unroll
  for (int kc = 0; kc < 4; ++kc){
    const s16x8 gv = *(const s16x8*)(g + abase + kc * 32);
    const s16x8 ov = *(const s16x8*)(o + abase + kc * 32);
    s16x8 r;
    #pragma unroll
    for (int j = 0; j < 8; ++j)
      r[j] = (short)f2bf(siluf(bf2f((unsigned short)gv[j])) * bf2f((unsigned short)ov[j]));
    af[kc] = r;
  }
  __syncthreads();
  #pragma unroll
  for (int ct = 0; ct < 4; ++ct){
    f32x4 acc = (f32x4)(0.0f);
    #pragma unroll
    for (int kc = 0; kc < 4; ++kc)
      acc = __builtin_amdgcn_mfma_f32_16x16x32_bf16(af[kc],
              *(const s16x8*)&wt[(ct * 16 + lr) * 136 + kc * 32 + lh * 8], acc, 0, 0, 0);
    #pragma unroll
    for (int j = 0; j < 4; ++j){
      const int row = rowbase + lh * 4 + j;
      const int col = y * 64 + ct * 16 + lr;
      const size_t idx = (size_t)row * 128 + col;
      outp[idx] = acc[j] + resid[idx];
    }
  }
}

// ---------------- dual GEMM with fused rms2: hh = gelu(h@W1)*(h@W2) ---------
__global__ __launch_bounds__(256) void k_dual(const float* __restrict__ x1,
    const float* __restrict__ ln2,
    const unsigned short* __restrict__ W1T, const unsigned short* __restrict__ W2T,
    unsigned short* __restrict__ hh){
  __shared__ unsigned short w1l[128 * 136];
  __shared__ unsigned short w2l[128 * 136];
  const int y = blockIdx.y;
  const int tid = threadIdx.x;
  #pragma unroll
  for (int c = 0; c < 8; ++c){
    const int id8 = c * 256 + tid;
    const int n = id8 >> 4, k8 = id8 & 15;
    *(uint4*)&w1l[n * 136 + k8 * 8] = *(const uint4*)&W1T[(size_t)(y * 128 + n) * 128 + k8 * 8];
    *(uint4*)&w2l[n * 136 + k8 * 8] = *(const uint4*)&W2T[(size_t)(y * 128 + n) * 128 + k8 * 8];
  }
  const int lane = tid & 63, wave = tid >> 6;
  const int lr = lane & 15, lh = lane >> 4;
  const int rowbase = blockIdx.x * 64 + wave * 16;
  const size_t xb = (size_t)(rowbase + lr) * 128 + lh * 8;
  float xv[32];
  float ss = 0.f;
  #pragma unroll
  for (int kc = 0; kc < 4; ++kc){
    const float4 a = *(const float4*)&x1[xb + kc * 32];
    const float4 b = *(const float4*)&x1[xb + kc * 32 + 4];
    xv[kc*8+0]=a.x; xv[kc*8+1]=a.y; xv[kc*8+2]=a.z; xv[kc*8+3]=a.w;
    xv[kc*8+4]=b.x; xv[kc*8+5]=b.y; xv[kc*8+6]=b.z; xv[kc*8+7]=b.w;
    ss += a.x*a.x + a.y*a.y + a.z*a.z + a.w*a.w;
    ss += b.x*b.x + b.y*b.y + b.z*b.z + b.w*b.w;
  }
  ss += __shfl_xor(ss, 16, 64);
  ss += __shfl_xor(ss, 32, 64);
  const float rs = rsqrtf(ss * (1.0f / 128.0f) + EPSF);
  s16x8 af[4];
  #pragma unroll
  for (int kc = 0; kc < 4; ++kc){
    const float4 w0 = *(const float4*)&ln2[kc * 32 + lh * 8];
    const float4 w1 = *(const float4*)&ln2[kc * 32 + lh * 8 + 4];
    s16x8 r;
    r[0]=(short)f2bf(xv[kc*8+0]*rs*w0.x); r[1]=(short)f2bf(xv[kc*8+1]*rs*w0.y);
    r[2]=(short)f2bf(xv[kc*8+2]*rs*w0.z); r[3]=(short)f2bf(xv[kc*8+3]*rs*w0.w);
    r[4]=(short)f2bf(xv[kc*8+4]*rs*w1.x); r[5]=(short)f2bf(xv[kc*8+5]*rs*w1.y);
    r[6]=(short)f2bf(xv[kc*8+6]*rs*w1.z); r[7]=(short)f2bf(xv[kc*8+7]*rs*w1.w);
    af[kc] = r;
  }
  __syncthreads();
  #pragma unroll
  for (int ct = 0; ct < 8; ++ct){
    f32x4 a1 = (f32x4)(0.0f), a2 = (f32x4)(0.0f);
    #pragma unroll
    for (int kc = 0; kc < 4; ++kc){
      a1 = __builtin_amdgcn_mfma_f32_16x16x32_bf16(af[kc],
             *(const s16x8*)&w1l[(ct * 16 + lr) * 136 + kc * 32 + lh * 8], a1, 0, 0, 0);
      a2 = __builtin_amdgcn_mfma_f32_16x16x32_bf16(af[kc],
             *(const s16x8*)&w2l[(ct * 16 + lr) * 136 + kc * 32 + lh * 8], a2, 0, 0, 0);
    }
    #pragma unroll
    for (int j = 0; j < 4; ++j){
      const int row = rowbase + lh * 4 + j;
      const int col = y * 128 + ct * 16 + lr;
      hh[(size_t)row * 256 + col] = f2bf(geluf(a1[j]) * a2[j]);
    }
  }
}

// ---------------- fc2 (K=256) + resid, LDS weights, col-split ---------------
__global__ __launch_bounds__(256) void k_fc2(const unsigned short* __restrict__ hh,
    const unsigned short* __restrict__ WT, const float* __restrict__ x1,
    float* __restrict__ outp){
  __shared__ unsigned short wt[64 * 264];
  const int y = blockIdx.y;
  const int tid = threadIdx.x;
  #pragma unroll
  for (int c = 0; c < 8; ++c){
    const int id8 = c * 256 + tid;
    const int n = id8 >> 5, k8 = id8 & 31;
    *(uint4*)&wt[n * 264 + k8 * 8] = *(const uint4*)&WT[(size_t)(y * 64 + n) * 256 + k8 * 8];
  }
  const int lane = tid & 63, wave = tid >> 6;
  const int lr = lane & 15, lh = lane >> 4;
  const int rowbase = blockIdx.x * 64 + wave * 16;
  s16x8 af[8];
  const unsigned short* arow = hh + (size_t)(rowbase + lr) * 256 + lh * 8;
  #pragma unroll
  for (int kc = 0; kc < 8; ++kc) af[kc] = *(const s16x8*)(arow + kc * 32);
  __syncthreads();
  #pragma unroll
  for (int ct = 0; ct < 4; ++ct){
    f32x4 acc = (f32x4)(0.0f);
    #pragma unroll
    for (int kc = 0; kc < 8; ++kc)
      acc = __builtin_amdgcn_mfma_f32_16x16x32_bf16(af[kc],
              *(const s16x8*)&wt[(ct * 16 + lr) * 264 + kc * 32 + lh * 8], acc, 0, 0, 0);
    #pragma unroll
    for (int j = 0; j < 4; ++j){
      const int row = rowbase + lh * 4 + j;
      const int col = y * 64 + ct * 16 + lr;
      const size_t idx = (size_t)row * 128 + col;
      outp[idx] = acc[j] + x1[idx];
    }
  }
}

// ---------------------------------------------------------------------------
extern "C" void kernel_launch(void* const* d_in, const int* in_sizes, int n_in,
                              void* d_out, int out_size, void* d_ws, size_t ws_size,
                              hipStream_t stream){
  const float* x     = (const float*)d_in[0];
  const float* pe    = (const float*)d_in[1];
  const int*   coords= (const int*)d_in[2];
  const float* Wq    = (const float*)d_in[3];
  const float* Wk    = (const float*)d_in[4];
  const float* Wv    = (const float*)d_in[5];
  const float* Wg    = (const float*)d_in[6];
  const float* Wo    = (const float*)d_in[7];
  const float* ln1   = (const float*)d_in[8];
  const float* ln2   = (const float*)d_in[9];
  const float* Wfc1  = (const float*)d_in[10];
  const float* Wgate = (const float*)d_in[11];
  const float* Wfc2  = (const float*)d_in[12];
  float* out = (float*)d_out;
  char* ws = (char*)d_ws;

  const size_t SZB = 4194304;   // BM*128 bf16 bytes
  unsigned short* qbf  = (unsigned short*)(ws);
  unsigned short* kbf  = (unsigned short*)(ws + 1 * SZB);
  unsigned short* vbf  = (unsigned short*)(ws + 2 * SZB);
  unsigned short* gbf  = (unsigned short*)(ws + 3 * SZB);
  unsigned short* obf  = (unsigned short*)(ws + 4 * SZB);
  float*          x1   = (float*)(ws + 5 * SZB);          // 8 MB f32
  unsigned short* hhb  = (unsigned short*)(ws + 5 * SZB + 8388608);  // 8 MB
  char* wbase = ws + 5 * SZB + 2 * 8388608;
  unsigned short* wqt   = (unsigned short*)(wbase);
  unsigned short* wkt   = (unsigned short*)(wbase + 32768);
  unsigned short* wvt   = (unsigned short*)(wbase + 65536);
  unsigned short* wgt   = (unsigned short*)(wbase + 98304);
  unsigned short* wot   = (unsigned short*)(wbase + 131072);
  unsigned short* fc1t  = (unsigned short*)(wbase + 163840);
  unsigned short* gatet = (unsigned short*)(wbase + 229376);
  unsigned short* fc2t  = (unsigned short*)(wbase + 294912);

  dim3 b256(256);
  k_wprep_all<<<704, b256, 0, stream>>>(Wq, Wk, Wv, Wg, Wo, Wfc1, Wgate, Wfc2,
                                        wqt, wkt, wvt, wgt, wot, fc1t, gatet, fc2t);
  k_qkvg2<<<dim3(256, 2), b256, 0, stream>>>(x, pe, ln1, wqt, wkt, wvt, wgt,
                                             qbf, kbf, vbf, gbf);
  k_attn<<<1024, b256, 0, stream>>>(qbf, kbf, vbf, coords, obf);
  k_wo<<<dim3(256, 2), b256, 0, stream>>>(gbf, obf, wot, x, x1);
  k_dual<<<dim3(256, 2), b256, 0, stream>>>(x1, ln2, fc1t, gatet, hhb);
  k_fc2<<<dim3(256, 2), b256, 0, stream>>>(hhb, fc2t, x1, out);
}

// Round 15
// 79.726 us; speedup vs baseline: 1.1126x; 1.1126x over previous
//
#include <hip/hip_runtime.h>

#define G_ 32
#define S_ 512
#define D_ 128
#define H_ 8
#define BM_ (G_*S_)
#define EPSF 1e-6f
#define VP_ 516   // vlT row stride (shorts): 1032B == 2 banks -> 16 rows hit 16 distinct even banks

typedef float f32x4  __attribute__((ext_vector_type(4)));
typedef float f32x16 __attribute__((ext_vector_type(16)));
typedef short s16x8  __attribute__((ext_vector_type(8)));

typedef unsigned int uint32;

#if __has_builtin(__builtin_amdgcn_exp2f)
#define EXP2F(x) __builtin_amdgcn_exp2f(x)
#else
#define EXP2F(x) exp2f(x)
#endif

static __device__ __forceinline__ unsigned short f2bf(float f){
  uint32 u = __float_as_uint(f);
  u = (u + 0x7fffu + ((u >> 16) & 1u)) >> 16;
  return (unsigned short)u;
}
static __device__ __forceinline__ float bf2f(unsigned short h){
  return __uint_as_float(((uint32)h) << 16);
}
static __device__ __forceinline__ float siluf(float x){
  float e = EXP2F(-x * 1.4426950408889634f);
  return x / (1.0f + e);
}
static __device__ __forceinline__ float geluf(float x){
  float y = 0.7978845608028654f * (x + 0.044715f * x * x * x);
  y = fminf(fmaxf(y, -40.0f), 40.0f);
  float e = EXP2F(y * 2.8853900817779268f);   // e^{2y}
  float th = (e - 1.0f) / (e + 1.0f);
  return 0.5f * x * (1.0f + th);
}
static __device__ __forceinline__ uint32 sad3(uint32 a, uint32 b){
#if __has_builtin(__builtin_amdgcn_sad_u8)
  return __builtin_amdgcn_sad_u8(a, b, 0u);
#else
  uint32 d; uint32 z = 0;
  asm("v_sad_u8 %0, %1, %2, %3" : "=v"(d) : "v"(a), "v"(b), "v"(z));
  return d;
#endif
}

// ---------------- all weight transposes, one flat launch --------------------
__global__ __launch_bounds__(256) void k_wprep_all(
    const float* __restrict__ w0, const float* __restrict__ w1,
    const float* __restrict__ w2, const float* __restrict__ w3,
    const float* __restrict__ w4, const float* __restrict__ w5,
    const float* __restrict__ w6, const float* __restrict__ w7,
    unsigned short* __restrict__ o0, unsigned short* __restrict__ o1,
    unsigned short* __restrict__ o2, unsigned short* __restrict__ o3,
    unsigned short* __restrict__ o4, unsigned short* __restrict__ o5,
    unsigned short* __restrict__ o6, unsigned short* __restrict__ o7){
  const int id = blockIdx.x * 256 + threadIdx.x;   // 0..180223
  const float* W; unsigned short* O; int Kd, Nd, lid;
  if (id < 81920){
    const int which = id >> 14;
    W = (which == 0) ? w0 : (which == 1) ? w1 : (which == 2) ? w2 : (which == 3) ? w3 : w4;
    O = (which == 0) ? o0 : (which == 1) ? o1 : (which == 2) ? o2 : (which == 3) ? o3 : o4;
    Kd = 128; Nd = 128; lid = id & 16383;
  } else if (id < 114688){ W = w5; O = o5; Kd = 128; Nd = 256; lid = id - 81920; }
  else if (id < 147456){   W = w6; O = o6; Kd = 128; Nd = 256; lid = id - 114688; }
  else if (id < 180224){   W = w7; O = o7; Kd = 256; Nd = 128; lid = id - 147456; }
  else return;
  const int n = lid / Kd, k = lid - n * Kd;
  O[lid] = f2bf(W[(size_t)k * Nd + n]);
}

// ---------------- QKVG projections with fused rms1(+pe) ---------------------
__global__ __launch_bounds__(512) void k_qkvg(
    const float* __restrict__ x, const float* __restrict__ pe,
    const float* __restrict__ ln1,
    const unsigned short* __restrict__ wqt, const unsigned short* __restrict__ wkt,
    const unsigned short* __restrict__ wvt, const unsigned short* __restrict__ wgt,
    unsigned short* __restrict__ qbf, unsigned short* __restrict__ kbf,
    unsigned short* __restrict__ vbf, unsigned short* __restrict__ gbf){
  __shared__ unsigned short wt[128 * 136];
  const int which = blockIdx.y;
  const unsigned short* WT = (which == 0) ? wqt : (which == 1) ? wkt : (which == 2) ? wvt : wgt;
  unsigned short* out      = (which == 0) ? qbf : (which == 1) ? kbf : (which == 2) ? vbf : gbf;
  const float scale = (which == 0) ? 0.36067376022224085f : 1.0f;  // HD^-0.5*log2e on q
  const int tid = threadIdx.x;
  #pragma unroll
  for (int c = 0; c < 4; ++c){
    const int id8 = c * 512 + tid;
    const int n = id8 >> 4, k8 = id8 & 15;
    *(uint4*)&wt[n * 136 + k8 * 8] = *(const uint4*)&WT[n * 128 + k8 * 8];
  }
  const int lane = tid & 63, wave = tid >> 6;
  const int lr = lane & 15, lh = lane >> 4;
  const int rowbase = blockIdx.x * 128 + wave * 16;
  const size_t xb = (size_t)(rowbase + lr) * 128 + lh * 8;
  float xv[32];
  float ss = 0.f;
  #pragma unroll
  for (int kc = 0; kc < 4; ++kc){
    const float4 a = *(const float4*)&x[xb + kc * 32];
    const float4 b = *(const float4*)&x[xb + kc * 32 + 4];
    xv[kc*8+0]=a.x; xv[kc*8+1]=a.y; xv[kc*8+2]=a.z; xv[kc*8+3]=a.w;
    xv[kc*8+4]=b.x; xv[kc*8+5]=b.y; xv[kc*8+6]=b.z; xv[kc*8+7]=b.w;
    ss += a.x*a.x + a.y*a.y + a.z*a.z + a.w*a.w;
    ss += b.x*b.x + b.y*b.y + b.z*b.z + b.w*b.w;
  }
  ss += __shfl_xor(ss, 16, 64);
  ss += __shfl_xor(ss, 32, 64);
  const float rs = rsqrtf(ss * (1.0f / 128.0f) + EPSF);
  s16x8 af[4];
  #pragma unroll
  for (int kc = 0; kc < 4; ++kc){
    const float4 w0 = *(const float4*)&ln1[kc * 32 + lh * 8];
    const float4 w1 = *(const float4*)&ln1[kc * 32 + lh * 8 + 4];
    float n0 = xv[kc*8+0]*rs*w0.x, n1 = xv[kc*8+1]*rs*w0.y;
    float n2 = xv[kc*8+2]*rs*w0.z, n3 = xv[kc*8+3]*rs*w0.w;
    float n4 = xv[kc*8+4]*rs*w1.x, n5 = xv[kc*8+5]*rs*w1.y;
    float n6 = xv[kc*8+6]*rs*w1.z, n7 = xv[kc*8+7]*rs*w1.w;
    if (which < 2){
      const float4 p0 = *(const float4*)&pe[xb + kc * 32];
      const float4 p1 = *(const float4*)&pe[xb + kc * 32 + 4];
      n0 += p0.x; n1 += p0.y; n2 += p0.z; n3 += p0.w;
      n4 += p1.x; n5 += p1.y; n6 += p1.z; n7 += p1.w;
    }
    s16x8 r;
    r[0]=(short)f2bf(n0); r[1]=(short)f2bf(n1); r[2]=(short)f2bf(n2); r[3]=(short)f2bf(n3);
    r[4]=(short)f2bf(n4); r[5]=(short)f2bf(n5); r[6]=(short)f2bf(n6); r[7]=(short)f2bf(n7);
    af[kc] = r;
  }
  __syncthreads();
  #pragma unroll
  for (int ct = 0; ct < 8; ++ct){
    f32x4 acc = (f32x4)(0.0f);
    #pragma unroll
    for (int kc = 0; kc < 4; ++kc)
      acc = __builtin_amdgcn_mfma_f32_16x16x32_bf16(af[kc],
              *(const s16x8*)&wt[(ct * 16 + lr) * 136 + kc * 32 + lh * 8], acc, 0, 0, 0);
    #pragma unroll
    for (int j = 0; j < 4; ++j){
      const int row = rowbase + lh * 4 + j;
      const int col = ct * 16 + lr;
      out[(size_t)row * 128 + col] = f2bf(acc[j] * scale);
    }
  }
}

// ---------------- retention attention: (g,head,qtile) per block -------------
// R11 best-passing structure: K from global (L2), e2 from LDS table.
__global__ __launch_bounds__(256, 4) void k_attn(const unsigned short* __restrict__ qb,
    const unsigned short* __restrict__ kb, const unsigned short* __restrict__ vb,
    const int* __restrict__ coords, unsigned short* __restrict__ ob){
  __shared__ unsigned short vlT[16 * VP_];     // 16.1 KB
  __shared__ uint32 cl1[S_];                   // 2 KB
  __shared__ float e2tab[384];                 // 1.5 KB
  const int bx = blockIdx.x;
  const int g = bx >> 5, head = (bx >> 2) & 7, qtile = bx & 3;
  const int tid = threadIdx.x;
  const size_t rb = (size_t)g * S_ * 128 + head * 16;
  const int lane = tid & 63, wave = tid >> 6;
  const int lq = lane & 31, half = lane >> 5;
  const int qrow = qtile * 128 + wave * 32 + lq;
  const s16x8 bq = *(const s16x8*)(qb + rb + (size_t)qrow * 128 + half * 8);  // before barrier
  const float decay2 = log2f(1.0f - EXP2F(-(float)(5 + head)));
  #pragma unroll
  for (int r = tid; r < S_; r += 256){
    const int4 cc = ((const int4*)coords)[g * S_ + r];
    cl1[r] = (uint32)(cc.y & 127) | ((uint32)(cc.z & 127) << 8) | ((uint32)(cc.w & 127) << 16);
  }
  for (int d = tid; d < 384; d += 256)
    e2tab[d] = EXP2F((float)d * decay2);       // same expression as inline -> bitwise equal
  {
    const int r0 = tid * 2;
    const unsigned short* v0 = vb + rb + (size_t)r0 * 128;
    const uint4 a0 = ((const uint4*)v0)[0], a1 = ((const uint4*)v0)[1];
    const uint4 b0 = ((const uint4*)(v0 + 128))[0], b1 = ((const uint4*)(v0 + 128))[1];
    const unsigned short* pa0 = (const unsigned short*)&a0;
    const unsigned short* pa1 = (const unsigned short*)&a1;
    const unsigned short* pb0 = (const unsigned short*)&b0;
    const unsigned short* pb1 = (const unsigned short*)&b1;
    #pragma unroll
    for (int hd = 0; hd < 8; ++hd){
      *(uint32*)&vlT[hd * VP_ + r0] = (uint32)pa0[hd] | ((uint32)pb0[hd] << 16);
      *(uint32*)&vlT[(hd + 8) * VP_ + r0] = (uint32)pa1[hd] | ((uint32)pb1[hd] << 16);
    }
  }
  __syncthreads();
  const uint32 cs = cl1[qrow];
  f32x16 accO = (f32x16)(0.0f);
  float2 zm0 = {0.f,0.f}, zm1 = {0.f,0.f}, zm2 = {0.f,0.f}, zm3 = {0.f,0.f};
  const int vrow = (lq & 15) * VP_;
  for (int tc = 0; tc < 16; ++tc){
    // K fragment straight from global (L2-resident)
    const s16x8 ak = *(const s16x8*)(kb + rb + (size_t)(tc * 32 + lq) * 128 + half * 8);
    const uint4 cq0 = *(const uint4*)&cl1[tc * 32 + 4 * half];
    const uint4 cq1 = *(const uint4*)&cl1[tc * 32 + 8 + 4 * half];
    const uint4 cq2 = *(const uint4*)&cl1[tc * 32 + 16 + 4 * half];
    const uint4 cq3 = *(const uint4*)&cl1[tc * 32 + 24 + 4 * half];
    // e2 lookups are independent of the MFMA result -> issue early
    float e2v[16];
    #pragma unroll
    for (int i = 0; i < 16; ++i){
      const uint4& cq = (i < 4) ? cq0 : (i < 8) ? cq1 : (i < 12) ? cq2 : cq3;
      e2v[i] = e2tab[sad3(cs, (&cq.x)[i & 3])];
    }
    const f32x16 c = __builtin_amdgcn_mfma_f32_32x32x16_bf16(ak, bq, (f32x16)(0.0f), 0, 0, 0);
    float wv[16];
    #pragma unroll
    for (int i = 0; i < 16; ++i){
      const float e1 = EXP2F(c[i]);        // exp(qk) (log2e folded into q)
      const float e2 = e2v[i];
      wv[i] = e1 * e2;
      float2& zm = (i & 2) ? ((i & 1) ? zm3 : zm2) : ((i & 1) ? zm1 : zm0);
      zm.x += e1; zm.y += e2;
    }
    union { uint32 u[4]; s16x8 v; } f0, f1;
    #pragma unroll
    for (int j = 0; j < 4; ++j){
      asm("v_cvt_pk_bf16_f32 %0, %1, %2" : "=v"(f0.u[j]) : "v"(wv[2 * j]), "v"(wv[2 * j + 1]));
      asm("v_cvt_pk_bf16_f32 %0, %1, %2" : "=v"(f1.u[j]) : "v"(wv[8 + 2 * j]), "v"(wv[9 + 2 * j]));
    }
    const int vcol = tc * 32 + 4 * half;
    union { uint32 u[4]; s16x8 v; } bv0, bv1;
    *(uint2*)&bv0.u[0] = *(const uint2*)&vlT[vrow + vcol];
    *(uint2*)&bv0.u[2] = *(const uint2*)&vlT[vrow + vcol + 8];
    *(uint2*)&bv1.u[0] = *(const uint2*)&vlT[vrow + vcol + 16];
    *(uint2*)&bv1.u[2] = *(const uint2*)&vlT[vrow + vcol + 24];
    accO = __builtin_amdgcn_mfma_f32_32x32x16_bf16(f0.v, bv0.v, accO, 0, 0, 0);
    accO = __builtin_amdgcn_mfma_f32_32x32x16_bf16(f1.v, bv1.v, accO, 0, 0, 0);
  }
  float Z = (zm0.x + zm1.x) + (zm2.x + zm3.x);
  float M = (zm0.y + zm1.y) + (zm2.y + zm3.y);
  Z += __shfl_xor(Z, 32, 64);
  M += __shfl_xor(M, 32, 64);
  const float sc = Z * sqrtf(M);          // denom==1 always (mask rowsum<=1)
  const float epsp = EPSF * sc * sc;
  const size_t qbase = (size_t)(g * S_ + qtile * 128 + wave * 32);
  const int sub = (lq >> 4);
  #pragma unroll
  for (int ii = 0; ii < 8; ++ii){
    const int i = sub * 8 + ii;
    const int r = (i & 3) + 8 * (i >> 2) + 4 * half;
    const float v = accO[i];
    float ss = v * v;
    ss += __shfl_xor(ss, 1, 64); ss += __shfl_xor(ss, 2, 64);
    ss += __shfl_xor(ss, 4, 64); ss += __shfl_xor(ss, 8, 64);
    const float ei = __shfl(epsp, r, 64);
    const float on = v * rsqrtf(ss * 0.0625f + ei);
    ob[(qbase + r) * 128 + head * 16 + (lq & 15)] = f2bf(on);
  }
}

// ---------------- Wo GEMM, LDS-staged weights, col-split --------------------
__global__ __launch_bounds__(256) void k_wo(const unsigned short* __restrict__ g,
    const unsigned short* __restrict__ o, const unsigned short* __restrict__ WT,
    const float* __restrict__ resid, float* __restrict__ outp){
  __shared__ unsigned short wt[64 * 136];
  const int y = blockIdx.y;
  const int tid = threadIdx.x;
  #pragma unroll
  for (int c = 0; c < 4; ++c){
    const int id8 = c * 256 + tid;
    const int n = id8 >> 4, k8 = id8 & 15;
    *(uint4*)&wt[n * 136 + k8 * 8] = *(const uint4*)&WT[(size_t)(y * 64 + n) * 128 + k8 * 8];
  }
  const int lane = tid & 63, wave = tid >> 6;
  const int lr = lane & 15, lh = lane >> 4;
  const int rowbase = blockIdx.x * 64 + wave * 16;
  s16x8 af[4];
  const size_t abase = (size_t)(rowbase + lr) * 128 + lh * 8;
  #pragma unroll
  for (int kc = 0; kc < 4; ++kc){
    const s16x8 gv = *(const s16x8*)(g + abase + kc * 32);
    const s16x8 ov = *(const s16x8*)(o + abase + kc * 32);
    s16x8 r;
    #pragma unroll
    for (int j = 0; j < 8; ++j)
      r[j] = (short)f2bf(siluf(bf2f((unsigned short)gv[j])) * bf2f((unsigned short)ov[j]));
    af[kc] = r;
  }
  __syncthreads();
  #pragma unroll
  for (int ct = 0; ct < 4; ++ct){
    f32x4 acc = (f32x4)(0.0f);
    #pragma unroll
    for (int kc = 0; kc < 4; ++kc)
      acc = __builtin_amdgcn_mfma_f32_16x16x32_bf16(af[kc],
              *(const s16x8*)&wt[(ct * 16 + lr) * 136 + kc * 32 + lh * 8], acc, 0, 0, 0);
    #pragma unroll
    for (int j = 0; j < 4; ++j){
      const int row = rowbase + lh * 4 + j;
      const int col = y * 64 + ct * 16 + lr;
      const size_t idx = (size_t)row * 128 + col;
      outp[idx] = acc[j] + resid[idx];
    }
  }
}

// ---------------- dual GEMM with fused rms2: hh = gelu(h@W1)*(h@W2) ---------
__global__ __launch_bounds__(256) void k_dual(const float* __restrict__ x1,
    const float* __restrict__ ln2,
    const unsigned short* __restrict__ W1T, const unsigned short* __restrict__ W2T,
    unsigned short* __restrict__ hh){
  __shared__ unsigned short w1l[128 * 136];
  __shared__ unsigned short w2l[128 * 136];
  const int y = blockIdx.y;
  const int tid = threadIdx.x;
  #pragma unroll
  for (int c = 0; c < 8; ++c){
    const int id8 = c * 256 + tid;
    const int n = id8 >> 4, k8 = id8 & 15;
    *(uint4*)&w1l[n * 136 + k8 * 8] = *(const uint4*)&W1T[(size_t)(y * 128 + n) * 128 + k8 * 8];
    *(uint4*)&w2l[n * 136 + k8 * 8] = *(const uint4*)&W2T[(size_t)(y * 128 + n) * 128 + k8 * 8];
  }
  const int lane = tid & 63, wave = tid >> 6;
  const int lr = lane & 15, lh = lane >> 4;
  const int rowbase = blockIdx.x * 64 + wave * 16;
  const size_t xb = (size_t)(rowbase + lr) * 128 + lh * 8;
  float xv[32];
  float ss = 0.f;
  #pragma unroll
  for (int kc = 0; kc < 4; ++kc){
    const float4 a = *(const float4*)&x1[xb + kc * 32];
    const float4 b = *(const float4*)&x1[xb + kc * 32 + 4];
    xv[kc*8+0]=a.x; xv[kc*8+1]=a.y; xv[kc*8+2]=a.z; xv[kc*8+3]=a.w;
    xv[kc*8+4]=b.x; xv[kc*8+5]=b.y; xv[kc*8+6]=b.z; xv[kc*8+7]=b.w;
    ss += a.x*a.x + a.y*a.y + a.z*a.z + a.w*a.w;
    ss += b.x*b.x + b.y*b.y + b.z*b.z + b.w*b.w;
  }
  ss += __shfl_xor(ss, 16, 64);
  ss += __shfl_xor(ss, 32, 64);
  const float rs = rsqrtf(ss * (1.0f / 128.0f) + EPSF);
  s16x8 af[4];
  #pragma unroll
  for (int kc = 0; kc < 4; ++kc){
    const float4 w0 = *(const float4*)&ln2[kc * 32 + lh * 8];
    const float4 w1 = *(const float4*)&ln2[kc * 32 + lh * 8 + 4];
    s16x8 r;
    r[0]=(short)f2bf(xv[kc*8+0]*rs*w0.x); r[1]=(short)f2bf(xv[kc*8+1]*rs*w0.y);
    r[2]=(short)f2bf(xv[kc*8+2]*rs*w0.z); r[3]=(short)f2bf(xv[kc*8+3]*rs*w0.w);
    r[4]=(short)f2bf(xv[kc*8+4]*rs*w1.x); r[5]=(short)f2bf(xv[kc*8+5]*rs*w1.y);
    r[6]=(short)f2bf(xv[kc*8+6]*rs*w1.z); r[7]=(short)f2bf(xv[kc*8+7]*rs*w1.w);
    af[kc] = r;
  }
  __syncthreads();
  #pragma unroll
  for (int ct = 0; ct < 8; ++ct){
    f32x4 a1 = (f32x4)(0.0f), a2 = (f32x4)(0.0f);
    #pragma unroll
    for (int kc = 0; kc < 4; ++kc){
      a1 = __builtin_amdgcn_mfma_f32_16x16x32_bf16(af[kc],
             *(const s16x8*)&w1l[(ct * 16 + lr) * 136 + kc * 32 + lh * 8], a1, 0, 0, 0);
      a2 = __builtin_amdgcn_mfma_f32_16x16x32_bf16(af[kc],
             *(const s16x8*)&w2l[(ct * 16 + lr) * 136 + kc * 32 + lh * 8], a2, 0, 0, 0);
    }
    #pragma unroll
    for (int j = 0; j < 4; ++j){
      const int row = rowbase + lh * 4 + j;
      const int col = y * 128 + ct * 16 + lr;
      hh[(size_t)row * 256 + col] = f2bf(geluf(a1[j]) * a2[j]);
    }
  }
}

// ---------------- fc2 (K=256) + resid, LDS weights, col-split ---------------
__global__ __launch_bounds__(256) void k_fc2(const unsigned short* __restrict__ hh,
    const unsigned short* __restrict__ WT, const float* __restrict__ x1,
    float* __restrict__ outp){
  __shared__ unsigned short wt[64 * 264];
  const int y = blockIdx.y;
  const int tid = threadIdx.x;
  #pragma unroll
  for (int c = 0; c < 8; ++c){
    const int id8 = c * 256 + tid;
    const int n = id8 >> 5, k8 = id8 & 31;
    *(uint4*)&wt[n * 264 + k8 * 8] = *(const uint4*)&WT[(size_t)(y * 64 + n) * 256 + k8 * 8];
  }
  const int lane = tid & 63, wave = tid >> 6;
  const int lr = lane & 15, lh = lane >> 4;
  const int rowbase = blockIdx.x * 64 + wave * 16;
  s16x8 af[8];
  const unsigned short* arow = hh + (size_t)(rowbase + lr) * 256 + lh * 8;
  #pragma unroll
  for (int kc = 0; kc < 8; ++kc) af[kc] = *(const s16x8*)(arow + kc * 32);
  __syncthreads();
  #pragma unroll
  for (int ct = 0; ct < 4; ++ct){
    f32x4 acc = (f32x4)(0.0f);
    #pragma unroll
    for (int kc = 0; kc < 8; ++kc)
      acc = __builtin_amdgcn_mfma_f32_16x16x32_bf16(af[kc],
              *(const s16x8*)&wt[(ct * 16 + lr) * 264 + kc * 32 + lh * 8], acc, 0, 0, 0);
    #pragma unroll
    for (int j = 0; j < 4; ++j){
      const int row = rowbase + lh * 4 + j;
      const int col = y * 64 + ct * 16 + lr;
      const size_t idx = (size_t)row * 128 + col;
      outp[idx] = acc[j] + x1[idx];
    }
  }
}

// ---------------------------------------------------------------------------
extern "C" void kernel_launch(void* const* d_in, const int* in_sizes, int n_in,
                              void* d_out, int out_size, void* d_ws, size_t ws_size,
                              hipStream_t stream){
  const float* x     = (const float*)d_in[0];
  const float* pe    = (const float*)d_in[1];
  const int*   coords= (const int*)d_in[2];
  const float* Wq    = (const float*)d_in[3];
  const float* Wk    = (const float*)d_in[4];
  const float* Wv    = (const float*)d_in[5];
  const float* Wg    = (const float*)d_in[6];
  const float* Wo    = (const float*)d_in[7];
  const float* ln1   = (const float*)d_in[8];
  const float* ln2   = (const float*)d_in[9];
  const float* Wfc1  = (const float*)d_in[10];
  const float* Wgate = (const float*)d_in[11];
  const float* Wfc2  = (const float*)d_in[12];
  float* out = (float*)d_out;
  char* ws = (char*)d_ws;

  const size_t SZB = 4194304;   // BM*128 bf16 bytes
  unsigned short* qbf  = (unsigned short*)(ws);
  unsigned short* kbf  = (unsigned short*)(ws + 1 * SZB);
  unsigned short* vbf  = (unsigned short*)(ws + 2 * SZB);
  unsigned short* gbf  = (unsigned short*)(ws + 3 * SZB);
  unsigned short* obf  = (unsigned short*)(ws + 4 * SZB);
  float*          x1   = (float*)(ws + 5 * SZB);          // 8 MB f32
  unsigned short* hhb  = (unsigned short*)(ws + 5 * SZB + 8388608);  // 8 MB
  char* wbase = ws + 5 * SZB + 2 * 8388608;
  unsigned short* wqt   = (unsigned short*)(wbase);
  unsigned short* wkt   = (unsigned short*)(wbase + 32768);
  unsigned short* wvt   = (unsigned short*)(wbase + 65536);
  unsigned short* wgt   = (unsigned short*)(wbase + 98304);
  unsigned short* wot   = (unsigned short*)(wbase + 131072);
  unsigned short* fc1t  = (unsigned short*)(wbase + 163840);
  unsigned short* gatet = (unsigned short*)(wbase + 229376);
  unsigned short* fc2t  = (unsigned short*)(wbase + 294912);

  dim3 b256(256);
  k_wprep_all<<<704, b256, 0, stream>>>(Wq, Wk, Wv, Wg, Wo, Wfc1, Wgate, Wfc2,
                                        wqt, wkt, wvt, wgt, wot, fc1t, gatet, fc2t);
  k_qkvg<<<dim3(128, 4), dim3(512), 0, stream>>>(x, pe, ln1, wqt, wkt, wvt, wgt,
                                                 qbf, kbf, vbf, gbf);
  k_attn<<<1024, b256, 0, stream>>>(qbf, kbf, vbf, coords, obf);
  k_wo<<<dim3(256, 2), b256, 0, stream>>>(gbf, obf, wot, x, x1);
  k_dual<<<dim3(256, 2), b256, 0, stream>>>(x1, ln2, fc1t, gatet, hhb);
  k_fc2<<<dim3(256, 2), b256, 0, stream>>>(hhb, fc2t, x1, out);
}